// Round 3
// baseline (257.456 us; speedup 1.0000x reference)
//
#include <hip/hip_runtime.h>

// CoL: out[p] = sum_{q in 3x3} W[q-p] * L[bin(x_q), bin(x_p)] * x_q
// B=32 C=64 H=128 W=128, L 5x5, zero pad, bin(x)=clamp(floor(5x),0,4).
//
// R3: row-streamed direct-gather kernel.
//  - LDS table WL[9][25] = W*L fused; (dr,dw) is a compile-time ds_read
//    immediate offset; per term = 1 v_add + ds_read_b32 + v_fmac.
//  - Bins quantized per window-row and consumed immediately (24 terms),
//    then the b20 array is reused -> small live set, no rematerialization
//    (R2's 44-VGPR allocation forced the compiler to recompute bins per
//    term: ~635 VALU/wave instead of ~310).
//  - Gathers issued in explicit batches of 24 -> one LDS latency
//    amortized across the batch.
//  - quantize: b=(int)fminf(x*5,4.0f) -- exact for x>=0 (trunc==floor,
//    float-min clamp at 4.0 == int clamp).
//  - 25-entry sub-tables span 25 distinct banks; duplicate-address lanes
//    broadcast -> conflict-free (confirmed: SQ_LDS_BANK_CONFLICT==0).

namespace {
constexpr int H  = 128;
constexpr int WD = 128;
constexpr int PLANES = 32 * 64;        // 2048
constexpr int PX  = 8;                 // pixels per thread
constexpr int TPR = WD / PX;           // 16 threads per row
constexpr int RPB = 32;                // rows per block
constexpr int THREADS = RPB * TPR;     // 512
constexpr int TILES = H / RPB;         // 4
}

__global__ __launch_bounds__(THREADS) void col_kernel(
    const float* __restrict__ x, const float* __restrict__ Wf,
    const float* __restrict__ Lf, float* __restrict__ out)
{
    __shared__ float WL[9 * 25];       // WL[(dr*3+dw)*25 + bq*5 + bp]
    const int t = threadIdx.x;
    if (t < 225) WL[t] = Wf[t / 25] * Lf[t % 25];
    __syncthreads();

    const int plane = blockIdx.x >> 2;           // / TILES
    const int row   = ((blockIdx.x & 3) << 5) + (t >> 4);
    const int col0  = (t & 15) * PX;
    const float* xp = x + (size_t)plane * (H * WD);

    // 3 rows x 10 cols window covering the 3x3 nbhd of 8 pixels.
    float win[3][PX + 2];
    #pragma unroll
    for (int dr = 0; dr < 3; ++dr) {
        const int rr = row + dr - 1;
        float4 c0 = make_float4(0.f, 0.f, 0.f, 0.f);
        float4 c1 = make_float4(0.f, 0.f, 0.f, 0.f);
        float l = 0.f, r = 0.f;
        if (rr >= 0 && rr < H) {
            const float* rp = xp + rr * WD + col0;
            c0 = *(const float4*)rp;             // 16B aligned
            c1 = *(const float4*)(rp + 4);
            if (col0 > 0)       l = rp[-1];      // exec-masked load
            if (col0 < WD - PX) r = rp[PX];
        }
        win[dr][0] = l;
        win[dr][1] = c0.x; win[dr][2] = c0.y; win[dr][3] = c0.z; win[dr][4] = c0.w;
        win[dr][5] = c1.x; win[dr][6] = c1.y; win[dr][7] = c1.z; win[dr][8] = c1.w;
        win[dr][9] = r;
    }

    const char* wlb = (const char*)WL;
    float acc[PX];
    #pragma unroll
    for (int i = 0; i < PX; ++i) acc[i] = 0.f;

    int bp4[PX];                        // center-pixel bin * 4 (byte)
    int b20[PX + 2];                    // window-row bin * 20 (byte), reused

    // 24 terms of one window row; drIdx is compile-time after inlining so
    // (drIdx*3+dw)*100 folds into the ds_read immediate offset.
    auto row_terms = [&](int drIdx, const float (&wr)[PX + 2]) {
        float tv[3][PX];
        #pragma unroll
        for (int dw = 0; dw < 3; ++dw)
            #pragma unroll
            for (int i = 0; i < PX; ++i)
                tv[dw][i] = *(const float*)(
                    wlb + (b20[i + dw] + bp4[i] + (drIdx * 3 + dw) * 100));
        #pragma unroll
        for (int dw = 0; dw < 3; ++dw)
            #pragma unroll
            for (int i = 0; i < PX; ++i)
                acc[i] = fmaf(tv[dw][i], wr[i + dw], acc[i]);
    };

    // Center row first: produces bp4, then its 24 terms.
    #pragma unroll
    for (int j = 0; j < PX + 2; ++j) {
        const int b  = (int)fminf(win[1][j] * 5.0f, 4.0f);
        const int b4 = b << 2;
        b20[j] = (b << 4) + b4;
        if (j >= 1 && j <= PX) bp4[j - 1] = b4;
    }
    row_terms(1, win[1]);

    // Top row.
    #pragma unroll
    for (int j = 0; j < PX + 2; ++j) {
        const int b = (int)fminf(win[0][j] * 5.0f, 4.0f);
        b20[j] = (b << 4) + (b << 2);
    }
    row_terms(0, win[0]);

    // Bottom row.
    #pragma unroll
    for (int j = 0; j < PX + 2; ++j) {
        const int b = (int)fminf(win[2][j] * 5.0f, 4.0f);
        b20[j] = (b << 4) + (b << 2);
    }
    row_terms(2, win[2]);

    float* op = out + (size_t)plane * (H * WD) + row * WD + col0;
    *(float4*)op       = make_float4(acc[0], acc[1], acc[2], acc[3]);
    *(float4*)(op + 4) = make_float4(acc[4], acc[5], acc[6], acc[7]);
}

extern "C" void kernel_launch(void* const* d_in, const int* in_sizes, int n_in,
                              void* d_out, int out_size, void* d_ws, size_t ws_size,
                              hipStream_t stream) {
    const float* x  = (const float*)d_in[0];   // input_tensor (B,C,H,W) fp32
    const float* Wf = (const float*)d_in[1];   // W (1,3,3) fp32
    const float* Lf = (const float*)d_in[2];   // L (5,5) fp32
    float* out = (float*)d_out;

    col_kernel<<<dim3(PLANES * TILES), dim3(THREADS), 0, stream>>>(x, Wf, Lf, out);
}